// Round 5
// baseline (635.899 us; speedup 1.0000x reference)
//
#include <hip/hip_runtime.h>

#define NHEAD 16
#define SEQ 2048
#define DMODEL 1024
#define BB 4
#define MROWS (BB*SEQ)      // 8192
#define NBH (BB*NHEAD)      // 64
#define NT (SEQ/32)         // 64 k-tiles

typedef float f32x4 __attribute__((ext_vector_type(4)));
typedef _Float16 f16x8 __attribute__((ext_vector_type(8)));
typedef _Float16 f16x4 __attribute__((ext_vector_type(4)));

static __device__ __forceinline__ f32x4 mfma16(f16x8 a, f16x8 b, f32x4 c) {
  return __builtin_amdgcn_mfma_f32_16x16x32_f16(a, b, c, 0, 0, 0);
}

static __device__ __forceinline__ void split2(float x, unsigned short& hi, unsigned short& lo) {
  _Float16 h = (_Float16)x;
  hi = __builtin_bit_cast(unsigned short, h);
  lo = __builtin_bit_cast(unsigned short, (_Float16)(x - (float)h));
}

static __device__ __forceinline__ void gload_lds16(const unsigned short* g, unsigned short* l) {
  __builtin_amdgcn_global_load_lds(
      (const __attribute__((address_space(1))) unsigned int*)g,
      (__attribute__((address_space(3))) unsigned int*)l, 16, 0, 0);
}

// fp32 -> f16 round (activations)
__global__ __launch_bounds__(256)
void round_f16(const float* __restrict__ src, unsigned short* __restrict__ dst, int n4)
{
  int i = blockIdx.x*256 + threadIdx.x;
  const int stride = gridDim.x*256;
  for (; i < n4; i += stride) {
    const float4 x = ((const float4*)src)[i];
    ushort4 h;
    h.x = __builtin_bit_cast(unsigned short, (_Float16)x.x);
    h.y = __builtin_bit_cast(unsigned short, (_Float16)x.y);
    h.z = __builtin_bit_cast(unsigned short, (_Float16)x.z);
    h.w = __builtin_bit_cast(unsigned short, (_Float16)x.w);
    ((ushort4*)dst)[i] = h;
  }
}

// fp32 -> hi/lo split (weights only)
__global__ __launch_bounds__(256)
void split_f32(const float* __restrict__ src, unsigned short* __restrict__ hi,
               unsigned short* __restrict__ lo, int n4)
{
  int i = blockIdx.x*256 + threadIdx.x;
  const int stride = gridDim.x*256;
  for (; i < n4; i += stride) {
    const float4 x = ((const float4*)src)[i];
    ushort4 h, l;
    split2(x.x, h.x, l.x); split2(x.y, h.y, l.y);
    split2(x.z, h.z, l.z); split2(x.w, h.w, l.w);
    ((ushort4*)hi)[i] = h;
    ((ushort4*)lo)[i] = l;
  }
}

// ---------------- projection GEMM: C = (X @ W^T + bias) * oscale ----------------
// X f16 [8192][1024]; W hi/lo f16 [1024][1024]. Tile 128x128, BK=32, 32 MFMA/kt.
// 3-deep LDS pipeline, prefetch distance 2, counted vmcnt.
// MODE 0: f16 [B,H,S,64] scaled;  MODE 1: f16 V^T [B,H,64,S];  MODE 2: fp32 [M,N]
static __device__ __forceinline__ void stage_proj(
    unsigned short* ab, unsigned short* bb,
    const unsigned short* __restrict__ Xf,
    const unsigned short* __restrict__ Wh, const unsigned short* __restrict__ Wl,
    int m0, int n0, int k0, int tid)
{
#pragma unroll
  for (int r = 0; r < 2; ++r) {            // A: 8KB
    const int gi = r*256 + tid;
    const int row = gi >> 2, c = gi & 3;
    const int lg = c ^ ((row >> 1) & 3);
    gload_lds16(Xf + (size_t)(m0+row)*DMODEL + k0 + lg*8,
                ab + r*2048 + (tid & 0xC0)*8);
  }
#pragma unroll
  for (int r = 0; r < 4; ++r) {            // B: 16KB
    const int gi = r*256 + tid;
    const int row = gi >> 3, c = gi & 7;
    const int sg = c ^ (row & 7);
    const unsigned short* src = (sg < 4)
        ? (Wh + (size_t)(n0+row)*DMODEL + k0 + sg*8)
        : (Wl + (size_t)(n0+row)*DMODEL + k0 + (sg-4)*8);
    gload_lds16(src, bb + r*2048 + (tid & 0xC0)*8);
  }
}

template<int MODE>
__global__ __launch_bounds__(256, 2)
void proj_gemm(const unsigned short* __restrict__ Xf,
               const unsigned short* __restrict__ Wh, const unsigned short* __restrict__ Wl,
               const float* __restrict__ bias, float oscale,
               unsigned short* __restrict__ o16, float* __restrict__ o_f32)
{
  __shared__ unsigned short As[3][128][32];   // 24KB
  __shared__ unsigned short Bs[3][128][64];   // 48KB
  const int tid  = threadIdx.x;
  const int wid  = tid >> 6, lane = tid & 63;
  const int g    = lane >> 4, r16 = lane & 15;
  const int id   = blockIdx.y*64 + blockIdx.x;
  const int xcd  = id & 7, slot = id >> 3;
  const int m0   = (xcd*8 + (slot & 7)) * 128;
  const int n0   = (slot >> 3) * 128;
  const int wr   = wid >> 1, wc = wid & 1;

  f32x4 acc[4][4] = {};

  stage_proj(&As[0][0][0], &Bs[0][0][0], Xf, Wh, Wl, m0, n0, 0,  tid);
  stage_proj(&As[1][0][0], &Bs[1][0][0], Xf, Wh, Wl, m0, n0, 32, tid);
  asm volatile("s_waitcnt vmcnt(6)" ::: "memory");
  __builtin_amdgcn_s_barrier();

  int bsel = 0;
  for (int kt = 0; kt < 32; ++kt) {
    int bnx = bsel + 2; if (bnx >= 3) bnx -= 3;
    if (kt < 30)
      stage_proj(&As[bnx][0][0], &Bs[bnx][0][0], Xf, Wh, Wl, m0, n0, (kt+2)*32, tid);

    const unsigned short (*Asb)[32] = As[bsel];
    const unsigned short (*Bsb)[64] = Bs[bsel];
    f16x8 a[4], b_h[4], b_l[4];
#pragma unroll
    for (int t = 0; t < 4; ++t) {
      const int ar = wr*64 + t*16 + r16;
      a[t] = *(const f16x8*)((const char*)&Asb[ar][0] + ((g ^ ((ar >> 1) & 3)) << 4));
      const int br = wc*64 + t*16 + r16;
      const char* pb = (const char*)&Bsb[br][0];
      b_h[t] = *(const f16x8*)(pb + (((g    ) ^ (br & 7)) << 4));
      b_l[t] = *(const f16x8*)(pb + (((4 | g) ^ (br & 7)) << 4));
    }
    __builtin_amdgcn_s_setprio(1);
#pragma unroll
    for (int mt = 0; mt < 4; ++mt)
#pragma unroll
      for (int nt = 0; nt < 4; ++nt) {
        acc[mt][nt] = mfma16(a[mt], b_h[nt], acc[mt][nt]);
        acc[mt][nt] = mfma16(a[mt], b_l[nt], acc[mt][nt]);
      }
    __builtin_amdgcn_s_setprio(0);

    if (kt < 30) {
      asm volatile("s_waitcnt vmcnt(6)" ::: "memory");
      __builtin_amdgcn_s_barrier();
    } else if (kt == 30) {
      asm volatile("s_waitcnt vmcnt(0)" ::: "memory");
      __builtin_amdgcn_s_barrier();
    }
    bsel = bsel + 1; if (bsel >= 3) bsel = 0;
  }

#pragma unroll
  for (int nt = 0; nt < 4; ++nt) {
    const int n  = n0 + wc*64 + nt*16 + r16;
    const float bn = bias[n];
#pragma unroll
    for (int mt = 0; mt < 4; ++mt) {
      const int mb = m0 + wr*64 + mt*16 + g*4;
      if (MODE == 0) {
#pragma unroll
        for (int j = 0; j < 4; ++j) {
          const int m = mb + j;
          const int bt = m >> 11, s = m & (SEQ-1);
          const int hh = n >> 6,  d = n & 63;
          o16[(((size_t)(bt*NHEAD + hh)*SEQ + s) << 6) + d] =
              __builtin_bit_cast(unsigned short, (_Float16)((acc[mt][nt][j] + bn) * oscale));
        }
      } else if (MODE == 1) {
        const int bt = mb >> 11, sb = mb & (SEQ-1);
        const int hh = n >> 6,  d = n & 63;
        ushort4 v;
        v.x = __builtin_bit_cast(unsigned short, (_Float16)(acc[mt][nt][0] + bn));
        v.y = __builtin_bit_cast(unsigned short, (_Float16)(acc[mt][nt][1] + bn));
        v.z = __builtin_bit_cast(unsigned short, (_Float16)(acc[mt][nt][2] + bn));
        v.w = __builtin_bit_cast(unsigned short, (_Float16)(acc[mt][nt][3] + bn));
        *(ushort4*)(o16 + ((size_t)(bt*NHEAD + hh)*64 + d)*SEQ + sb) = v;
      } else {
#pragma unroll
        for (int j = 0; j < 4; ++j)
          o_f32[(size_t)(mb + j)*DMODEL + n] = acc[mt][nt][j] + bn;
      }
    }
  }
}

// ---------------- attention ----------------
// Ks tiles [32 k][64 u16]: rows 128B, granule 0-7 = d-chunks, swz ^(row&7)
// Vs tiles [64 d][32 u16]: rows 64B, granule 0-3 = k-chunks, swz ^((row>>1)&3)
// PA[wave][16 q][40 u16]: rows 80B, granule 0-3 = k-chunks, swz ^(q&3)
static __device__ __forceinline__ void stage_k(unsigned short* dst,
    const unsigned short* __restrict__ Kf, size_t kbase, int k0, int tid)
{
  const int row = tid >> 3, c = tid & 7;
  const int sg = c ^ (row & 7);
  gload_lds16(Kf + kbase + (size_t)(k0+row)*64 + sg*8, dst + (tid & 0xC0)*8);
}

static __device__ __forceinline__ void stage_v(unsigned short* dst,
    const unsigned short* __restrict__ Vtg, int bh, int k0, int tid)
{
  const int row = tid >> 2, c = tid & 3;
  const int lg = c ^ ((row >> 1) & 3);
  gload_lds16(Vtg + ((size_t)bh*64 + row)*SEQ + k0 + lg*8, dst + (tid & 0xC0)*8);
}

// pass 1: li = 1 / sum_k 2^(s') per q-row.  Q pre-scaled by 0.125*log2(e).
__global__ __launch_bounds__(256, 6)
void attn_l(const unsigned short* __restrict__ Qf, const unsigned short* __restrict__ Kf,
            float* __restrict__ lrow)
{
  __shared__ unsigned short Ks[6][32][64];   // 24KB, 3 chunks of 2 tiles
  const int tid = threadIdx.x, wid = tid >> 6, lane = tid & 63;
  const int g = lane >> 4, r16 = lane & 15;
  const int id = blockIdx.y*32 + blockIdx.x;
  const int xcd = id & 7, slot = id >> 3;
  const int bh = (slot >> 5)*8 + xcd;
  const int bx = slot & 31;
  const int s0 = bx*64 + wid*16;
  const size_t kbase = (size_t)bh*SEQ*64;

  const size_t qoff = ((size_t)bh*SEQ + s0 + r16)*64 + (size_t)g*8;
  const f16x8 qh0 = *(const f16x8*)(Qf + qoff);
  const f16x8 qh1 = *(const f16x8*)(Qf + qoff + 32);

  float lp = 0.f;
  stage_k(&Ks[0][0][0], Kf, kbase, 0,  tid);
  stage_k(&Ks[1][0][0], Kf, kbase, 32, tid);
  stage_k(&Ks[2][0][0], Kf, kbase, 64, tid);
  stage_k(&Ks[3][0][0], Kf, kbase, 96, tid);
  asm volatile("s_waitcnt vmcnt(2)" ::: "memory");
  __builtin_amdgcn_s_barrier();

  int b0 = 0;
  for (int c = 0; c < 32; ++c) {
    if (c < 30) {
      int bn = b0 + 4; if (bn >= 6) bn -= 6;
      stage_k(&Ks[bn  ][0][0], Kf, kbase, (c+2)*64,      tid);
      stage_k(&Ks[bn+1][0][0], Kf, kbase, (c+2)*64 + 32, tid);
    }
#pragma unroll
    for (int t = 0; t < 2; ++t) {
      const unsigned short (*Kt)[64] = Ks[b0 + t];
#pragma unroll
      for (int sub = 0; sub < 2; ++sub) {
        const int krow = sub*16 + r16;
        const char* pk = (const char*)&Kt[krow][0];
        const int sx = krow & 7;
        const f16x8 kh0 = *(const f16x8*)(pk + (((g    ) ^ sx) << 4));
        const f16x8 kh1 = *(const f16x8*)(pk + (((4 | g) ^ sx) << 4));
        f32x4 acc = {};
        __builtin_amdgcn_s_setprio(1);
        acc = mfma16(kh0, qh0, acc);
        acc = mfma16(kh1, qh1, acc);
        __builtin_amdgcn_s_setprio(0);
#pragma unroll
        for (int j = 0; j < 4; ++j) lp += __builtin_exp2f(acc[j]);
      }
    }
    if (c < 30) {
      asm volatile("s_waitcnt vmcnt(2)" ::: "memory");
      __builtin_amdgcn_s_barrier();
    } else if (c == 30) {
      asm volatile("s_waitcnt vmcnt(0)" ::: "memory");
      __builtin_amdgcn_s_barrier();
    }
    b0 += 2; if (b0 >= 6) b0 = 0;
  }
  lp += __shfl_xor(lp, 16);
  lp += __shfl_xor(lp, 32);
  if (lane < 16) lrow[(size_t)bh*SEQ + s0 + r16] = 1.0f / lp;
}

// pass 2: weights (normalized, fp32, NT stores) + PV -> Of (f16)
__global__ __launch_bounds__(256, 4)
void attn_wv(const unsigned short* __restrict__ Qf, const unsigned short* __restrict__ Kf,
             const unsigned short* __restrict__ Vtg, const float* __restrict__ lrow,
             float* __restrict__ wout, unsigned short* __restrict__ of16)
{
  __shared__ unsigned short Ks[4][32][64];   // 16 KB
  __shared__ unsigned short Vs[4][64][32];   // 16 KB
  __shared__ unsigned short PA[4][16][40];   // 5 KB
  const int tid = threadIdx.x, wid = tid >> 6, lane = tid & 63;
  const int g = lane >> 4, r16 = lane & 15;
  const int id = blockIdx.y*32 + blockIdx.x;
  const int xcd = id & 7, slot = id >> 3;
  const int bh = (slot >> 5)*8 + xcd;
  const int bx = slot & 31;
  const int bt = bh >> 4, hh = bh & (NHEAD-1);
  const int s0 = bx*64 + wid*16;
  const size_t kbase = (size_t)bh*SEQ*64;

  const size_t qoff = ((size_t)bh*SEQ + s0 + r16)*64 + (size_t)g*8;
  const f16x8 qh0 = *(const f16x8*)(Qf + qoff);
  const f16x8 qh1 = *(const f16x8*)(Qf + qoff + 32);
  const float li = lrow[(size_t)bh*SEQ + s0 + r16];

  f32x4 acco[4] = {};
  char* paw = (char*)&PA[wid][0][0];

  stage_k(&Ks[0][0][0], Kf, kbase, 0, tid);
  stage_v(&Vs[0][0][0], Vtg, bh, 0, tid);
  stage_k(&Ks[1][0][0], Kf, kbase, 32, tid);
  stage_v(&Vs[1][0][0], Vtg, bh, 32, tid);
  asm volatile("s_waitcnt vmcnt(2)" ::: "memory");
  __builtin_amdgcn_s_barrier();

  for (int kt = 0; kt < NT; ++kt) {
    const int cur = kt & 3;
    if (kt < NT-2) {
      stage_k(&Ks[(kt+2)&3][0][0], Kf, kbase, (kt+2)*32, tid);
      stage_v(&Vs[(kt+2)&3][0][0], Vtg, bh, (kt+2)*32, tid);
    }
#pragma unroll
    for (int sub = 0; sub < 2; ++sub) {
      const int krow = sub*16 + r16;
      const char* pk = (const char*)&Ks[cur][krow][0];
      const int sx = krow & 7;
      const f16x8 kh0 = *(const f16x8*)(pk + (((g    ) ^ sx) << 4));
      const f16x8 kh1 = *(const f16x8*)(pk + (((4 | g) ^ sx) << 4));
      f32x4 acc = {};
      __builtin_amdgcn_s_setprio(1);
      acc = mfma16(kh0, qh0, acc);
      acc = mfma16(kh1, qh1, acc);
      __builtin_amdgcn_s_setprio(0);
      f32x4 w4;
      f16x4 p4;
#pragma unroll
      for (int j = 0; j < 4; ++j) {
        w4[j] = __builtin_exp2f(acc[j]) * li;
        p4[j] = (_Float16)w4[j];
      }
      float* wp = wout + ((size_t)bh*SEQ + s0 + r16)*SEQ + kt*32 + sub*16 + 4*g;
      __builtin_nontemporal_store(w4, (f32x4*)wp);
      *(f16x4*)(paw + r16*80 + ((((2*sub + (g >> 1)) ^ (r16 & 3)) << 4) | ((g & 1) << 3))) = p4;
    }
    asm volatile("s_waitcnt lgkmcnt(0)" ::: "memory");
    const f16x8 pa = *(const f16x8*)(paw + r16*80 + ((g ^ (r16 & 3)) << 4));
    __builtin_amdgcn_s_setprio(1);
#pragma unroll
    for (int nt = 0; nt < 4; ++nt) {
      const int vrow = nt*16 + r16;
      const f16x8 vv = *(const f16x8*)((const char*)&Vs[cur][vrow][0] +
                                       ((g ^ ((vrow >> 1) & 3)) << 4));
      acco[nt] = mfma16(pa, vv, acco[nt]);
    }
    __builtin_amdgcn_s_setprio(0);
    // counted vmcnt: retire exactly K/V of kt+1; stores get a 2-iter window.
    if (kt == 0) {
      asm volatile("s_waitcnt vmcnt(4)" ::: "memory"); __builtin_amdgcn_s_barrier();
    } else if (kt < NT-2) {
      asm volatile("s_waitcnt vmcnt(6)" ::: "memory"); __builtin_amdgcn_s_barrier();
    } else if (kt == NT-2) {
      asm volatile("s_waitcnt vmcnt(4)" ::: "memory"); __builtin_amdgcn_s_barrier();
    }
  }

#pragma unroll
  for (int nt = 0; nt < 4; ++nt)
#pragma unroll
    for (int j = 0; j < 4; ++j)
      of16[((size_t)bt*SEQ + s0 + 4*g + j)*DMODEL + hh*64 + nt*16 + r16] =
          __builtin_bit_cast(unsigned short, (_Float16)acco[nt][j]);
}

extern "C" void kernel_launch(void* const* d_in, const int* in_sizes, int n_in,
                              void* d_out, int out_size, void* d_ws, size_t ws_size,
                              hipStream_t stream)
{
  const float* query = (const float*)d_in[0];
  const float* key_  = (const float*)d_in[1];
  const float* value = (const float*)d_in[2];
  const float* Wq = (const float*)d_in[3];
  const float* bq = (const float*)d_in[4];
  const float* Wk = (const float*)d_in[5];
  const float* bk = (const float*)d_in[6];
  const float* Wv = (const float*)d_in[7];
  const float* bv = (const float*)d_in[8];
  const float* Wo = (const float*)d_in[9];
  const float* bo = (const float*)d_in[10];

  const size_t NE = (size_t)NBH * SEQ * 64;        // 8,388,608
  unsigned short* X16 = (unsigned short*)d_ws;     // activation f16 (reused)
  unsigned short* Qf  = X16 + NE;
  unsigned short* Kf  = Qf + NE;
  unsigned short* Vt  = Kf + NE;                   // V^T [B,H,64,S]
  unsigned short* Of  = Vt + NE;                   // attn out f16 [M][D]
  unsigned short* WH  = Of + NE;
  unsigned short* WL  = WH + (size_t)DMODEL*DMODEL;
  float* lrow = (float*)(WL + (size_t)DMODEL*DMODEL);  // 1/l per row

  float* out0  = (float*)d_out;
  float* wattn = out0 + (size_t)MROWS * DMODEL;

  const int nX4 = MROWS*DMODEL/4, nW4 = DMODEL*DMODEL/4;
  const float QSCALE = 0.125f * 1.4426950408889634f;   // fold 1/sqrt(64) * log2(e)
  dim3 gg(64, 8);

  round_f16<<<1024, 256, 0, stream>>>(query, X16, nX4);
  split_f32<<<512,  256, 0, stream>>>(Wq, WH, WL, nW4);
  proj_gemm<0><<<gg, dim3(256), 0, stream>>>(X16, WH, WL, bq, QSCALE, Qf, nullptr);

  round_f16<<<1024, 256, 0, stream>>>(key_, X16, nX4);
  split_f32<<<512,  256, 0, stream>>>(Wk, WH, WL, nW4);
  proj_gemm<0><<<gg, dim3(256), 0, stream>>>(X16, WH, WL, bk, 1.0f, Kf, nullptr);

  round_f16<<<1024, 256, 0, stream>>>(value, X16, nX4);
  split_f32<<<512,  256, 0, stream>>>(Wv, WH, WL, nW4);
  proj_gemm<1><<<gg, dim3(256), 0, stream>>>(X16, WH, WL, bv, 1.0f, Vt, nullptr);

  attn_l <<<dim3(32, NBH), dim3(256), 0, stream>>>(Qf, Kf, lrow);
  attn_wv<<<dim3(32, NBH), dim3(256), 0, stream>>>(Qf, Kf, Vt, lrow, wattn, Of);

  split_f32<<<512,  256, 0, stream>>>(Wo, WH, WL, nW4);
  proj_gemm<2><<<gg, dim3(256), 0, stream>>>(Of, WH, WL, bo, 1.0f, nullptr, out0);
}

// Round 6
// 558.338 us; speedup vs baseline: 1.1389x; 1.1389x over previous
//
#include <hip/hip_runtime.h>

#define NHEAD 16
#define SEQ 2048
#define DMODEL 1024
#define BB 4
#define MROWS (BB*SEQ)      // 8192
#define NBH (BB*NHEAD)      // 64
#define NT (SEQ/32)         // 64 k-tiles

typedef float f32x4 __attribute__((ext_vector_type(4)));
typedef _Float16 f16x8 __attribute__((ext_vector_type(8)));
typedef _Float16 f16x4 __attribute__((ext_vector_type(4)));

static __device__ __forceinline__ f32x4 mfma16(f16x8 a, f16x8 b, f32x4 c) {
  return __builtin_amdgcn_mfma_f32_16x16x32_f16(a, b, c, 0, 0, 0);
}

static __device__ __forceinline__ void split2(float x, unsigned short& hi, unsigned short& lo) {
  _Float16 h = (_Float16)x;
  hi = __builtin_bit_cast(unsigned short, h);
  lo = __builtin_bit_cast(unsigned short, (_Float16)(x - (float)h));
}

static __device__ __forceinline__ void gload_lds16(const unsigned short* g, unsigned short* l) {
  __builtin_amdgcn_global_load_lds(
      (const __attribute__((address_space(1))) unsigned int*)g,
      (__attribute__((address_space(3))) unsigned int*)l, 16, 0, 0);
}

// fp32 -> f16 round (activations)
__global__ __launch_bounds__(256)
void round_f16(const float* __restrict__ src, unsigned short* __restrict__ dst, int n4)
{
  int i = blockIdx.x*256 + threadIdx.x;
  const int stride = gridDim.x*256;
  for (; i < n4; i += stride) {
    const float4 x = ((const float4*)src)[i];
    ushort4 h;
    h.x = __builtin_bit_cast(unsigned short, (_Float16)x.x);
    h.y = __builtin_bit_cast(unsigned short, (_Float16)x.y);
    h.z = __builtin_bit_cast(unsigned short, (_Float16)x.z);
    h.w = __builtin_bit_cast(unsigned short, (_Float16)x.w);
    ((ushort4*)dst)[i] = h;
  }
}

// fp32 -> hi/lo split (weights only)
__global__ __launch_bounds__(256)
void split_f32(const float* __restrict__ src, unsigned short* __restrict__ hi,
               unsigned short* __restrict__ lo, int n4)
{
  int i = blockIdx.x*256 + threadIdx.x;
  const int stride = gridDim.x*256;
  for (; i < n4; i += stride) {
    const float4 x = ((const float4*)src)[i];
    ushort4 h, l;
    split2(x.x, h.x, l.x); split2(x.y, h.y, l.y);
    split2(x.z, h.z, l.z); split2(x.w, h.w, l.w);
    ((ushort4*)hi)[i] = h;
    ((ushort4*)lo)[i] = l;
  }
}

// ---------------- projection GEMM: C = (X @ W^T + bias) * oscale ----------------
// X f16 [8192][1024]; W hi/lo f16 [1024][1024]. Tile 128x128, BK=32, 32 MFMA/kt.
// 2-buffer T3-minimum pipeline: stage(t+1) at loop head, vmcnt(0)+barrier at tail.
// MODE 0: f16 [B,H,S,64] scaled;  MODE 1: f16 V^T [B,H,64,S];  MODE 2: fp32 [M,N]
static __device__ __forceinline__ void stage_proj(
    unsigned short* ab, unsigned short* bb,
    const unsigned short* __restrict__ Xf,
    const unsigned short* __restrict__ Wh, const unsigned short* __restrict__ Wl,
    int m0, int n0, int k0, int tid)
{
#pragma unroll
  for (int r = 0; r < 2; ++r) {            // A: 8KB
    const int gi = r*256 + tid;
    const int row = gi >> 2, c = gi & 3;
    const int lg = c ^ ((row >> 1) & 3);
    gload_lds16(Xf + (size_t)(m0+row)*DMODEL + k0 + lg*8,
                ab + r*2048 + (tid & 0xC0)*8);
  }
#pragma unroll
  for (int r = 0; r < 4; ++r) {            // B: 16KB
    const int gi = r*256 + tid;
    const int row = gi >> 3, c = gi & 7;
    const int sg = c ^ (row & 7);
    const unsigned short* src = (sg < 4)
        ? (Wh + (size_t)(n0+row)*DMODEL + k0 + sg*8)
        : (Wl + (size_t)(n0+row)*DMODEL + k0 + (sg-4)*8);
    gload_lds16(src, bb + r*2048 + (tid & 0xC0)*8);
  }
}

template<int MODE>
__global__ __launch_bounds__(256, 3)
void proj_gemm(const unsigned short* __restrict__ Xf,
               const unsigned short* __restrict__ Wh, const unsigned short* __restrict__ Wl,
               const float* __restrict__ bias, float oscale,
               unsigned short* __restrict__ o16, float* __restrict__ o_f32)
{
  __shared__ unsigned short As[2][128][32];   // 16KB
  __shared__ unsigned short Bs[2][128][64];   // 32KB
  const int tid  = threadIdx.x;
  const int wid  = tid >> 6, lane = tid & 63;
  const int g    = lane >> 4, r16 = lane & 15;
  const int id   = blockIdx.y*64 + blockIdx.x;
  const int xcd  = id & 7, slot = id >> 3;
  const int m0   = (xcd*8 + (slot & 7)) * 128;
  const int n0   = (slot >> 3) * 128;
  const int wr   = wid >> 1, wc = wid & 1;

  f32x4 acc[4][4] = {};

  stage_proj(&As[0][0][0], &Bs[0][0][0], Xf, Wh, Wl, m0, n0, 0, tid);
  asm volatile("s_waitcnt vmcnt(0)" ::: "memory");
  __builtin_amdgcn_s_barrier();

  for (int kt = 0; kt < 32; ++kt) {
    const int cur = kt & 1;
    if (kt < 31)
      stage_proj(&As[cur^1][0][0], &Bs[cur^1][0][0], Xf, Wh, Wl, m0, n0, (kt+1)*32, tid);

    const unsigned short (*Asb)[32] = As[cur];
    const unsigned short (*Bsb)[64] = Bs[cur];
    f16x8 a[4], b_h[4], b_l[4];
#pragma unroll
    for (int t = 0; t < 4; ++t) {
      const int ar = wr*64 + t*16 + r16;
      a[t] = *(const f16x8*)((const char*)&Asb[ar][0] + ((g ^ ((ar >> 1) & 3)) << 4));
      const int br = wc*64 + t*16 + r16;
      const char* pb = (const char*)&Bsb[br][0];
      b_h[t] = *(const f16x8*)(pb + (((g    ) ^ (br & 7)) << 4));
      b_l[t] = *(const f16x8*)(pb + (((4 | g) ^ (br & 7)) << 4));
    }
    __builtin_amdgcn_s_setprio(1);
#pragma unroll
    for (int mt = 0; mt < 4; ++mt)
#pragma unroll
      for (int nt = 0; nt < 4; ++nt) {
        acc[mt][nt] = mfma16(a[mt], b_h[nt], acc[mt][nt]);
        acc[mt][nt] = mfma16(a[mt], b_l[nt], acc[mt][nt]);
      }
    __builtin_amdgcn_s_setprio(0);

    if (kt < 31) {
      asm volatile("s_waitcnt vmcnt(0)" ::: "memory");
      __builtin_amdgcn_s_barrier();
    }
  }

#pragma unroll
  for (int nt = 0; nt < 4; ++nt) {
    const int n  = n0 + wc*64 + nt*16 + r16;
    const float bn = bias[n];
#pragma unroll
    for (int mt = 0; mt < 4; ++mt) {
      const int mb = m0 + wr*64 + mt*16 + g*4;
      if (MODE == 0) {
#pragma unroll
        for (int j = 0; j < 4; ++j) {
          const int m = mb + j;
          const int bt = m >> 11, s = m & (SEQ-1);
          const int hh = n >> 6,  d = n & 63;
          o16[(((size_t)(bt*NHEAD + hh)*SEQ + s) << 6) + d] =
              __builtin_bit_cast(unsigned short, (_Float16)((acc[mt][nt][j] + bn) * oscale));
        }
      } else if (MODE == 1) {
        const int bt = mb >> 11, sb = mb & (SEQ-1);
        const int hh = n >> 6,  d = n & 63;
        ushort4 v;
        v.x = __builtin_bit_cast(unsigned short, (_Float16)(acc[mt][nt][0] + bn));
        v.y = __builtin_bit_cast(unsigned short, (_Float16)(acc[mt][nt][1] + bn));
        v.z = __builtin_bit_cast(unsigned short, (_Float16)(acc[mt][nt][2] + bn));
        v.w = __builtin_bit_cast(unsigned short, (_Float16)(acc[mt][nt][3] + bn));
        *(ushort4*)(o16 + ((size_t)(bt*NHEAD + hh)*64 + d)*SEQ + sb) = v;
      } else {
#pragma unroll
        for (int j = 0; j < 4; ++j)
          o_f32[(size_t)(mb + j)*DMODEL + n] = acc[mt][nt][j] + bn;
      }
    }
  }
}

// ---------------- fused attention ----------------
// Ks[buf][32 k][64 u16]: rows 128B, granule 0-7 = d-chunks, swz ^(row&7)
// Vs[buf][64 d][32 u16]: rows 64B, granule 0-3 = k-chunks, swz ^((row>>1)&3)
// PA[wave][16 q][40 u16]: rows 80B, granule 0-3 = k-chunks, swz ^(q&3)
static __device__ __forceinline__ void stage_k(unsigned short* dst,
    const unsigned short* __restrict__ Kf, size_t kbase, int k0, int tid)
{
  const int row = tid >> 3, c = tid & 7;
  const int sg = c ^ (row & 7);
  gload_lds16(Kf + kbase + (size_t)(k0+row)*64 + sg*8, dst + (tid & 0xC0)*8);
}

static __device__ __forceinline__ void stage_v(unsigned short* dst,
    const unsigned short* __restrict__ Vtg, int bh, int k0, int tid)
{
  const int row = tid >> 2, c = tid & 3;
  const int lg = c ^ ((row >> 1) & 3);
  gload_lds16(Vtg + ((size_t)bh*64 + row)*SEQ + k0 + lg*8, dst + (tid & 0xC0)*8);
}

__global__ __launch_bounds__(256, 4)
void attn_fused(const unsigned short* __restrict__ Qf, const unsigned short* __restrict__ Kf,
                const unsigned short* __restrict__ Vtg,
                float* __restrict__ wout, unsigned short* __restrict__ of16)
{
  __shared__ unsigned short Ks[4][32][64];   // 16 KB
  __shared__ unsigned short Vs[4][64][32];   // 16 KB
  __shared__ unsigned short PA[4][16][40];   // 5 KB
  const int tid = threadIdx.x, wid = tid >> 6, lane = tid & 63;
  const int g = lane >> 4, r16 = lane & 15;
  const int id = blockIdx.y*32 + blockIdx.x;
  const int xcd = id & 7, slot = id >> 3;
  const int bh = (slot >> 5)*8 + xcd;
  const int bx = slot & 31;
  const int bt = bh >> 4, hh = bh & (NHEAD-1);
  const int s0 = bx*64 + wid*16;
  const size_t kbase = (size_t)bh*SEQ*64;

  const size_t qoff = ((size_t)bh*SEQ + s0 + r16)*64 + (size_t)g*8;
  const f16x8 qh0 = *(const f16x8*)(Qf + qoff);      // Q pre-scaled by 0.125*log2(e)
  const f16x8 qh1 = *(const f16x8*)(Qf + qoff + 32);

  // ---- pass 1: l = sum 2^s'  (no max subtraction; scores bounded) ----
  float lp = 0.f;
  stage_k(&Ks[0][0][0], Kf, kbase, 0, tid);
  stage_k(&Ks[1][0][0], Kf, kbase, 32, tid);
  asm volatile("s_waitcnt vmcnt(1)" ::: "memory");
  __builtin_amdgcn_s_barrier();
  for (int kt = 0; kt < NT; ++kt) {
    const int cur = kt & 3;
    const bool pf = kt < NT-2;
    if (pf) stage_k(&Ks[(kt+2)&3][0][0], Kf, kbase, (kt+2)*32, tid);
#pragma unroll
    for (int sub = 0; sub < 2; ++sub) {
      const int krow = sub*16 + r16;
      const char* pk = (const char*)&Ks[cur][krow][0];
      const int sx = krow & 7;
      const f16x8 kh0 = *(const f16x8*)(pk + (((g    ) ^ sx) << 4));
      const f16x8 kh1 = *(const f16x8*)(pk + (((4 | g) ^ sx) << 4));
      f32x4 acc = {};
      __builtin_amdgcn_s_setprio(1);
      acc = mfma16(kh0, qh0, acc);
      acc = mfma16(kh1, qh1, acc);
      __builtin_amdgcn_s_setprio(0);
#pragma unroll
      for (int j = 0; j < 4; ++j) lp += __builtin_exp2f(acc[j]);
    }
    if (pf) { asm volatile("s_waitcnt vmcnt(1)" ::: "memory"); }
    else    { asm volatile("s_waitcnt vmcnt(0)" ::: "memory"); }
    __builtin_amdgcn_s_barrier();
  }
  lp += __shfl_xor(lp, 16);
  lp += __shfl_xor(lp, 32);
  const float li = 1.0f / lp;

  // ---- pass 2: weights + PV ----
  f32x4 acco[4] = {};
  char* paw = (char*)&PA[wid][0][0];

  stage_k(&Ks[0][0][0], Kf, kbase, 0, tid);
  stage_v(&Vs[0][0][0], Vtg, bh, 0, tid);
  stage_k(&Ks[1][0][0], Kf, kbase, 32, tid);
  stage_v(&Vs[1][0][0], Vtg, bh, 32, tid);
  asm volatile("s_waitcnt vmcnt(2)" ::: "memory");
  __builtin_amdgcn_s_barrier();
  for (int kt = 0; kt < NT; ++kt) {
    const int cur = kt & 3;
    if (kt < NT-2) {
      stage_k(&Ks[(kt+2)&3][0][0], Kf, kbase, (kt+2)*32, tid);
      stage_v(&Vs[(kt+2)&3][0][0], Vtg, bh, (kt+2)*32, tid);
    }
#pragma unroll
    for (int sub = 0; sub < 2; ++sub) {
      const int krow = sub*16 + r16;
      const char* pk = (const char*)&Ks[cur][krow][0];
      const int sx = krow & 7;
      const f16x8 kh0 = *(const f16x8*)(pk + (((g    ) ^ sx) << 4));
      const f16x8 kh1 = *(const f16x8*)(pk + (((4 | g) ^ sx) << 4));
      f32x4 acc = {};
      __builtin_amdgcn_s_setprio(1);
      acc = mfma16(kh0, qh0, acc);
      acc = mfma16(kh1, qh1, acc);
      __builtin_amdgcn_s_setprio(0);
      f32x4 w4;
      f16x4 p4;
#pragma unroll
      for (int j = 0; j < 4; ++j) {
        w4[j] = __builtin_exp2f(acc[j]) * li;
        p4[j] = (_Float16)w4[j];
      }
      float* wp = wout + ((size_t)bh*SEQ + s0 + r16)*SEQ + kt*32 + sub*16 + 4*g;
      __builtin_nontemporal_store(w4, (f32x4*)wp);
      *(f16x4*)(paw + r16*80 + ((((2*sub + (g >> 1)) ^ (r16 & 3)) << 4) | ((g & 1) << 3))) = p4;
    }
    asm volatile("s_waitcnt lgkmcnt(0)" ::: "memory");
    const f16x8 pa = *(const f16x8*)(paw + r16*80 + ((g ^ (r16 & 3)) << 4));
    __builtin_amdgcn_s_setprio(1);
#pragma unroll
    for (int nt = 0; nt < 4; ++nt) {
      const int vrow = nt*16 + r16;
      const f16x8 vv = *(const f16x8*)((const char*)&Vs[cur][vrow][0] +
                                       ((g ^ ((vrow >> 1) & 3)) << 4));
      acco[nt] = mfma16(pa, vv, acco[nt]);
    }
    __builtin_amdgcn_s_setprio(0);
    // counted vmcnt: retire exactly K/V(kt+1); weight stores get a ~2-iter window.
    if (kt == 0) {
      asm volatile("s_waitcnt vmcnt(4)" ::: "memory"); __builtin_amdgcn_s_barrier();
    } else if (kt < NT-2) {
      asm volatile("s_waitcnt vmcnt(6)" ::: "memory"); __builtin_amdgcn_s_barrier();
    } else if (kt == NT-2) {
      asm volatile("s_waitcnt vmcnt(4)" ::: "memory"); __builtin_amdgcn_s_barrier();
    }
  }

#pragma unroll
  for (int nt = 0; nt < 4; ++nt)
#pragma unroll
    for (int j = 0; j < 4; ++j)
      of16[((size_t)bt*SEQ + s0 + 4*g + j)*DMODEL + hh*64 + nt*16 + r16] =
          __builtin_bit_cast(unsigned short, (_Float16)acco[nt][j]);
}

extern "C" void kernel_launch(void* const* d_in, const int* in_sizes, int n_in,
                              void* d_out, int out_size, void* d_ws, size_t ws_size,
                              hipStream_t stream)
{
  const float* query = (const float*)d_in[0];
  const float* key_  = (const float*)d_in[1];
  const float* value = (const float*)d_in[2];
  const float* Wq = (const float*)d_in[3];
  const float* bq = (const float*)d_in[4];
  const float* Wk = (const float*)d_in[5];
  const float* bk = (const float*)d_in[6];
  const float* Wv = (const float*)d_in[7];
  const float* bv = (const float*)d_in[8];
  const float* Wo = (const float*)d_in[9];
  const float* bo = (const float*)d_in[10];

  const size_t NE = (size_t)NBH * SEQ * 64;        // 8,388,608
  unsigned short* X16 = (unsigned short*)d_ws;     // activation f16 (reused)
  unsigned short* Qf  = X16 + NE;
  unsigned short* Kf  = Qf + NE;
  unsigned short* Vt  = Kf + NE;                   // V^T [B,H,64,S]
  unsigned short* Of  = Vt + NE;                   // attn out f16 [M][D]
  unsigned short* WH  = Of + NE;
  unsigned short* WL  = WH + (size_t)DMODEL*DMODEL;

  float* out0  = (float*)d_out;
  float* wattn = out0 + (size_t)MROWS * DMODEL;

  const int nX4 = MROWS*DMODEL/4, nW4 = DMODEL*DMODEL/4;
  const float QSCALE = 0.125f * 1.4426950408889634f;   // fold 1/sqrt(64) * log2(e)
  dim3 gg(64, 8);

  round_f16<<<1024, 256, 0, stream>>>(query, X16, nX4);
  split_f32<<<512,  256, 0, stream>>>(Wq, WH, WL, nW4);
  proj_gemm<0><<<gg, dim3(256), 0, stream>>>(X16, WH, WL, bq, QSCALE, Qf, nullptr);

  round_f16<<<1024, 256, 0, stream>>>(key_, X16, nX4);
  split_f32<<<512,  256, 0, stream>>>(Wk, WH, WL, nW4);
  proj_gemm<0><<<gg, dim3(256), 0, stream>>>(X16, WH, WL, bk, 1.0f, Kf, nullptr);

  round_f16<<<1024, 256, 0, stream>>>(value, X16, nX4);
  split_f32<<<512,  256, 0, stream>>>(Wv, WH, WL, nW4);
  proj_gemm<1><<<gg, dim3(256), 0, stream>>>(X16, WH, WL, bv, 1.0f, Vt, nullptr);

  attn_fused<<<dim3(32, NBH), dim3(256), 0, stream>>>(Qf, Kf, Vt, wattn, Of);

  split_f32<<<512,  256, 0, stream>>>(Wo, WH, WL, nW4);
  proj_gemm<2><<<gg, dim3(256), 0, stream>>>(Of, WH, WL, bo, 1.0f, nullptr, out0);
}

// Round 7
// 496.244 us; speedup vs baseline: 1.2814x; 1.1251x over previous
//
#include <hip/hip_runtime.h>

#define NHEAD 16
#define SEQ 2048
#define DMODEL 1024
#define BB 4
#define MROWS (BB*SEQ)      // 8192
#define NBH (BB*NHEAD)      // 64
#define NT (SEQ/32)         // 64 k-tiles

typedef float f32x4 __attribute__((ext_vector_type(4)));
typedef _Float16 f16x8 __attribute__((ext_vector_type(8)));
typedef _Float16 f16x4 __attribute__((ext_vector_type(4)));

static __device__ __forceinline__ f32x4 mfma16(f16x8 a, f16x8 b, f32x4 c) {
  return __builtin_amdgcn_mfma_f32_16x16x32_f16(a, b, c, 0, 0, 0);
}

static __device__ __forceinline__ void gload_lds16(const unsigned short* g, unsigned short* l) {
  __builtin_amdgcn_global_load_lds(
      (const __attribute__((address_space(1))) unsigned int*)g,
      (__attribute__((address_space(3))) unsigned int*)l, 16, 0, 0);
}

static __device__ __forceinline__ ushort4 cvt4(float4 x) {
  ushort4 h;
  h.x = __builtin_bit_cast(unsigned short, (_Float16)x.x);
  h.y = __builtin_bit_cast(unsigned short, (_Float16)x.y);
  h.z = __builtin_bit_cast(unsigned short, (_Float16)x.z);
  h.w = __builtin_bit_cast(unsigned short, (_Float16)x.w);
  return h;
}

// fp32 -> f16 round: three activation tensors in one launch (blockIdx.y selects)
__global__ __launch_bounds__(256)
void round3_f16(const float* __restrict__ q, const float* __restrict__ k,
                const float* __restrict__ v,
                unsigned short* __restrict__ oq, unsigned short* __restrict__ ok,
                unsigned short* __restrict__ ov, int n4)
{
  const float* src = (blockIdx.y == 0) ? q : (blockIdx.y == 1) ? k : v;
  unsigned short* dst = (blockIdx.y == 0) ? oq : (blockIdx.y == 1) ? ok : ov;
  int i = blockIdx.x*256 + threadIdx.x;
  const int stride = gridDim.x*256;
  for (; i < n4; i += stride)
    ((ushort4*)dst)[i] = cvt4(((const float4*)src)[i]);
}

// fp32 -> f16 round: four weight matrices in one launch
__global__ __launch_bounds__(256)
void round_w4(const float* __restrict__ w0, const float* __restrict__ w1,
              const float* __restrict__ w2, const float* __restrict__ w3,
              unsigned short* __restrict__ o0, unsigned short* __restrict__ o1,
              unsigned short* __restrict__ o2, unsigned short* __restrict__ o3, int n4)
{
  const float* src = (blockIdx.y == 0) ? w0 : (blockIdx.y == 1) ? w1
                   : (blockIdx.y == 2) ? w2 : w3;
  unsigned short* dst = (blockIdx.y == 0) ? o0 : (blockIdx.y == 1) ? o1
                      : (blockIdx.y == 2) ? o2 : o3;
  int i = blockIdx.x*256 + threadIdx.x;
  const int stride = gridDim.x*256;
  for (; i < n4; i += stride)
    ((ushort4*)dst)[i] = cvt4(((const float4*)src)[i]);
}

// ---------------- projection GEMM: C = (X @ W^T + bias) * oscale ----------------
// X f16 [8192][1024]; W f16 [1024][1024]. Tile 128x128, BK=32, 16 MFMA/kt.
// 2-buffer pipeline: stage(t+1) at loop head, vmcnt(0)+barrier at tail.
// LDS tiles: rows 64B = 4 granules of 16B, swizzle granule ^= (row>>1)&3.
// MODE 0: f16 [B,H,S,64] scaled;  MODE 1: f16 V^T [B,H,64,S];  MODE 2: fp32 [M,N]
static __device__ __forceinline__ void stage_proj(
    unsigned short* ab, unsigned short* bb,
    const unsigned short* __restrict__ Xf, const unsigned short* __restrict__ Wf,
    int m0, int n0, int k0, int tid)
{
#pragma unroll
  for (int r = 0; r < 2; ++r) {            // A: 8KB
    const int gi = r*256 + tid;
    const int row = gi >> 2, c = gi & 3;
    const int lg = c ^ ((row >> 1) & 3);
    gload_lds16(Xf + (size_t)(m0+row)*DMODEL + k0 + lg*8,
                ab + r*2048 + (tid & 0xC0)*8);
  }
#pragma unroll
  for (int r = 0; r < 2; ++r) {            // B: 8KB
    const int gi = r*256 + tid;
    const int row = gi >> 2, c = gi & 3;
    const int lg = c ^ ((row >> 1) & 3);
    gload_lds16(Wf + (size_t)(n0+row)*DMODEL + k0 + lg*8,
                bb + r*2048 + (tid & 0xC0)*8);
  }
}

template<int MODE>
__global__ __launch_bounds__(256, 2)
void proj_gemm(const unsigned short* __restrict__ Xf, const unsigned short* __restrict__ Wf,
               const float* __restrict__ bias, float oscale,
               unsigned short* __restrict__ o16, float* __restrict__ o_f32)
{
  __shared__ unsigned short As[2][128][32];   // 16KB
  __shared__ unsigned short Bs[2][128][32];   // 16KB
  const int tid  = threadIdx.x;
  const int wid  = tid >> 6, lane = tid & 63;
  const int g    = lane >> 4, r16 = lane & 15;
  const int id   = blockIdx.y*64 + blockIdx.x;
  const int xcd  = id & 7, slot = id >> 3;
  const int m0   = (xcd*8 + (slot & 7)) * 128;
  const int n0   = (slot >> 3) * 128;
  const int wr   = wid >> 1, wc = wid & 1;

  f32x4 acc[4][4] = {};

  stage_proj(&As[0][0][0], &Bs[0][0][0], Xf, Wf, m0, n0, 0, tid);
  asm volatile("s_waitcnt vmcnt(0)" ::: "memory");
  __builtin_amdgcn_s_barrier();

  for (int kt = 0; kt < 32; ++kt) {
    const int cur = kt & 1;
    if (kt < 31)
      stage_proj(&As[cur^1][0][0], &Bs[cur^1][0][0], Xf, Wf, m0, n0, (kt+1)*32, tid);

    const unsigned short (*Asb)[32] = As[cur];
    const unsigned short (*Bsb)[32] = Bs[cur];
    f16x8 a[4], b[4];
#pragma unroll
    for (int t = 0; t < 4; ++t) {
      const int ar = wr*64 + t*16 + r16;
      a[t] = *(const f16x8*)((const char*)&Asb[ar][0] + ((g ^ ((ar >> 1) & 3)) << 4));
      const int br = wc*64 + t*16 + r16;
      b[t] = *(const f16x8*)((const char*)&Bsb[br][0] + ((g ^ ((br >> 1) & 3)) << 4));
    }
    __builtin_amdgcn_s_setprio(1);
#pragma unroll
    for (int mt = 0; mt < 4; ++mt)
#pragma unroll
      for (int nt = 0; nt < 4; ++nt)
        acc[mt][nt] = mfma16(a[mt], b[nt], acc[mt][nt]);
    __builtin_amdgcn_s_setprio(0);

    if (kt < 31) {
      asm volatile("s_waitcnt vmcnt(0)" ::: "memory");
      __builtin_amdgcn_s_barrier();
    }
  }

#pragma unroll
  for (int nt = 0; nt < 4; ++nt) {
    const int n  = n0 + wc*64 + nt*16 + r16;
    const float bn = bias[n];
#pragma unroll
    for (int mt = 0; mt < 4; ++mt) {
      const int mb = m0 + wr*64 + mt*16 + g*4;
      if (MODE == 0) {
#pragma unroll
        for (int j = 0; j < 4; ++j) {
          const int m = mb + j;
          const int bt = m >> 11, s = m & (SEQ-1);
          const int hh = n >> 6,  d = n & 63;
          o16[(((size_t)(bt*NHEAD + hh)*SEQ + s) << 6) + d] =
              __builtin_bit_cast(unsigned short, (_Float16)((acc[mt][nt][j] + bn) * oscale));
        }
      } else if (MODE == 1) {
        const int bt = mb >> 11, sb = mb & (SEQ-1);
        const int hh = n >> 6,  d = n & 63;
        ushort4 v;
        v.x = __builtin_bit_cast(unsigned short, (_Float16)(acc[mt][nt][0] + bn));
        v.y = __builtin_bit_cast(unsigned short, (_Float16)(acc[mt][nt][1] + bn));
        v.z = __builtin_bit_cast(unsigned short, (_Float16)(acc[mt][nt][2] + bn));
        v.w = __builtin_bit_cast(unsigned short, (_Float16)(acc[mt][nt][3] + bn));
        *(ushort4*)(o16 + ((size_t)(bt*NHEAD + hh)*64 + d)*SEQ + sb) = v;
      } else {
#pragma unroll
        for (int j = 0; j < 4; ++j)
          o_f32[(size_t)(mb + j)*DMODEL + n] = acc[mt][nt][j] + bn;
      }
    }
  }
}

// ---------------- fused attention ----------------
// Ks[buf][32 k][64 u16]: rows 128B, granule 0-7 = d-chunks, swz ^(row&7)
// Vs[buf][64 d][32 u16]: rows 64B, granule 0-3 = k-chunks, swz ^((row>>1)&3)
// PA[wave][16 q][40 u16]: rows 80B, granule 0-3 = k-chunks, swz ^(q&3)
static __device__ __forceinline__ void stage_k(unsigned short* dst,
    const unsigned short* __restrict__ Kf, size_t kbase, int k0, int tid)
{
  const int row = tid >> 3, c = tid & 7;
  const int sg = c ^ (row & 7);
  gload_lds16(Kf + kbase + (size_t)(k0+row)*64 + sg*8, dst + (tid & 0xC0)*8);
}

static __device__ __forceinline__ void stage_v(unsigned short* dst,
    const unsigned short* __restrict__ Vtg, int bh, int k0, int tid)
{
  const int row = tid >> 2, c = tid & 3;
  const int lg = c ^ ((row >> 1) & 3);
  gload_lds16(Vtg + ((size_t)bh*64 + row)*SEQ + k0 + lg*8, dst + (tid & 0xC0)*8);
}

__global__ __launch_bounds__(256, 4)
void attn_fused(const unsigned short* __restrict__ Qf, const unsigned short* __restrict__ Kf,
                const unsigned short* __restrict__ Vtg,
                float* __restrict__ wout, unsigned short* __restrict__ of16)
{
  __shared__ unsigned short Ks[4][32][64];   // 16 KB
  __shared__ unsigned short Vs[4][64][32];   // 16 KB
  __shared__ unsigned short PA[4][16][40];   // 5 KB
  const int tid = threadIdx.x, wid = tid >> 6, lane = tid & 63;
  const int g = lane >> 4, r16 = lane & 15;
  const int id = blockIdx.y*32 + blockIdx.x;
  const int xcd = id & 7, slot = id >> 3;
  const int bh = (slot >> 5)*8 + xcd;
  const int bx = slot & 31;
  const int bt = bh >> 4, hh = bh & (NHEAD-1);
  const int s0 = bx*64 + wid*16;
  const size_t kbase = (size_t)bh*SEQ*64;

  const size_t qoff = ((size_t)bh*SEQ + s0 + r16)*64 + (size_t)g*8;
  const f16x8 qh0 = *(const f16x8*)(Qf + qoff);      // Q pre-scaled by 0.125*log2(e)
  const f16x8 qh1 = *(const f16x8*)(Qf + qoff + 32);

  // ---- pass 1: l = sum 2^s'  (no max subtraction; scores bounded) ----
  float lp = 0.f;
  stage_k(&Ks[0][0][0], Kf, kbase, 0, tid);
  stage_k(&Ks[1][0][0], Kf, kbase, 32, tid);
  asm volatile("s_waitcnt vmcnt(1)" ::: "memory");
  __builtin_amdgcn_s_barrier();
  for (int kt = 0; kt < NT; ++kt) {
    const int cur = kt & 3;
    const bool pf = kt < NT-2;
    if (pf) stage_k(&Ks[(kt+2)&3][0][0], Kf, kbase, (kt+2)*32, tid);
#pragma unroll
    for (int sub = 0; sub < 2; ++sub) {
      const int krow = sub*16 + r16;
      const char* pk = (const char*)&Ks[cur][krow][0];
      const int sx = krow & 7;
      const f16x8 kh0 = *(const f16x8*)(pk + (((g    ) ^ sx) << 4));
      const f16x8 kh1 = *(const f16x8*)(pk + (((4 | g) ^ sx) << 4));
      f32x4 acc = {};
      __builtin_amdgcn_s_setprio(1);
      acc = mfma16(kh0, qh0, acc);
      acc = mfma16(kh1, qh1, acc);
      __builtin_amdgcn_s_setprio(0);
#pragma unroll
      for (int j = 0; j < 4; ++j) lp += __builtin_exp2f(acc[j]);
    }
    if (pf) { asm volatile("s_waitcnt vmcnt(1)" ::: "memory"); }
    else    { asm volatile("s_waitcnt vmcnt(0)" ::: "memory"); }
    __builtin_amdgcn_s_barrier();
  }
  lp += __shfl_xor(lp, 16);
  lp += __shfl_xor(lp, 32);
  const float li = 1.0f / lp;

  // ---- pass 2: weights + PV ----
  f32x4 acco[4] = {};
  char* paw = (char*)&PA[wid][0][0];

  stage_k(&Ks[0][0][0], Kf, kbase, 0, tid);
  stage_v(&Vs[0][0][0], Vtg, bh, 0, tid);
  stage_k(&Ks[1][0][0], Kf, kbase, 32, tid);
  stage_v(&Vs[1][0][0], Vtg, bh, 32, tid);
  asm volatile("s_waitcnt vmcnt(2)" ::: "memory");
  __builtin_amdgcn_s_barrier();
  for (int kt = 0; kt < NT; ++kt) {
    const int cur = kt & 3;
    if (kt < NT-2) {
      stage_k(&Ks[(kt+2)&3][0][0], Kf, kbase, (kt+2)*32, tid);
      stage_v(&Vs[(kt+2)&3][0][0], Vtg, bh, (kt+2)*32, tid);
    }
#pragma unroll
    for (int sub = 0; sub < 2; ++sub) {
      const int krow = sub*16 + r16;
      const char* pk = (const char*)&Ks[cur][krow][0];
      const int sx = krow & 7;
      const f16x8 kh0 = *(const f16x8*)(pk + (((g    ) ^ sx) << 4));
      const f16x8 kh1 = *(const f16x8*)(pk + (((4 | g) ^ sx) << 4));
      f32x4 acc = {};
      __builtin_amdgcn_s_setprio(1);
      acc = mfma16(kh0, qh0, acc);
      acc = mfma16(kh1, qh1, acc);
      __builtin_amdgcn_s_setprio(0);
      f32x4 w4;
      f16x4 p4;
#pragma unroll
      for (int j = 0; j < 4; ++j) {
        w4[j] = __builtin_exp2f(acc[j]) * li;
        p4[j] = (_Float16)w4[j];
      }
      float* wp = wout + ((size_t)bh*SEQ + s0 + r16)*SEQ + kt*32 + sub*16 + 4*g;
      __builtin_nontemporal_store(w4, (f32x4*)wp);
      *(f16x4*)(paw + r16*80 + ((((2*sub + (g >> 1)) ^ (r16 & 3)) << 4) | ((g & 1) << 3))) = p4;
    }
    asm volatile("s_waitcnt lgkmcnt(0)" ::: "memory");
    const f16x8 pa = *(const f16x8*)(paw + r16*80 + ((g ^ (r16 & 3)) << 4));
    __builtin_amdgcn_s_setprio(1);
#pragma unroll
    for (int nt = 0; nt < 4; ++nt) {
      const int vrow = nt*16 + r16;
      const f16x8 vv = *(const f16x8*)((const char*)&Vs[cur][vrow][0] +
                                       ((g ^ ((vrow >> 1) & 3)) << 4));
      acco[nt] = mfma16(pa, vv, acco[nt]);
    }
    __builtin_amdgcn_s_setprio(0);
    // counted vmcnt: retire exactly K/V(kt+1); weight stores get a ~2-iter window.
    if (kt == 0) {
      asm volatile("s_waitcnt vmcnt(4)" ::: "memory"); __builtin_amdgcn_s_barrier();
    } else if (kt < NT-2) {
      asm volatile("s_waitcnt vmcnt(6)" ::: "memory"); __builtin_amdgcn_s_barrier();
    } else if (kt == NT-2) {
      asm volatile("s_waitcnt vmcnt(4)" ::: "memory"); __builtin_amdgcn_s_barrier();
    }
  }

#pragma unroll
  for (int nt = 0; nt < 4; ++nt)
#pragma unroll
    for (int j = 0; j < 4; ++j)
      of16[((size_t)bt*SEQ + s0 + 4*g + j)*DMODEL + hh*64 + nt*16 + r16] =
          __builtin_bit_cast(unsigned short, (_Float16)acco[nt][j]);
}

extern "C" void kernel_launch(void* const* d_in, const int* in_sizes, int n_in,
                              void* d_out, int out_size, void* d_ws, size_t ws_size,
                              hipStream_t stream)
{
  const float* query = (const float*)d_in[0];
  const float* key_  = (const float*)d_in[1];
  const float* value = (const float*)d_in[2];
  const float* Wq = (const float*)d_in[3];
  const float* bq = (const float*)d_in[4];
  const float* Wk = (const float*)d_in[5];
  const float* bk = (const float*)d_in[6];
  const float* Wv = (const float*)d_in[7];
  const float* bv = (const float*)d_in[8];
  const float* Wo = (const float*)d_in[9];
  const float* bo = (const float*)d_in[10];

  const size_t NE = (size_t)NBH * SEQ * 64;        // 8,388,608
  const size_t NW = (size_t)DMODEL * DMODEL;       // 1,048,576
  unsigned short* Xq16 = (unsigned short*)d_ws;    // reused as Of after attn
  unsigned short* Xk16 = Xq16 + NE;
  unsigned short* Xv16 = Xk16 + NE;
  unsigned short* Qf   = Xv16 + NE;
  unsigned short* Kf   = Qf + NE;
  unsigned short* Vt   = Kf + NE;                  // V^T [B,H,64,S]
  unsigned short* Wq16 = Vt + NE;
  unsigned short* Wk16 = Wq16 + NW;
  unsigned short* Wv16 = Wk16 + NW;
  unsigned short* Wo16 = Wv16 + NW;
  unsigned short* Of   = Xq16;                     // overlay (Xq16 dead after Q proj)

  float* out0  = (float*)d_out;
  float* wattn = out0 + (size_t)MROWS * DMODEL;

  const int nX4 = MROWS*DMODEL/4, nW4 = DMODEL*DMODEL/4;
  const float QSCALE = 0.125f * 1.4426950408889634f;   // fold 1/sqrt(64) * log2(e)
  dim3 gg(64, 8);

  round3_f16<<<dim3(1024, 3), 256, 0, stream>>>(query, key_, value, Xq16, Xk16, Xv16, nX4);
  round_w4<<<dim3(256, 4), 256, 0, stream>>>(Wq, Wk, Wv, Wo, Wq16, Wk16, Wv16, Wo16, nW4);

  proj_gemm<0><<<gg, dim3(256), 0, stream>>>(Xq16, Wq16, bq, QSCALE, Qf, nullptr);
  proj_gemm<0><<<gg, dim3(256), 0, stream>>>(Xk16, Wk16, bk, 1.0f, Kf, nullptr);
  proj_gemm<1><<<gg, dim3(256), 0, stream>>>(Xv16, Wv16, bv, 1.0f, Vt, nullptr);

  attn_fused<<<dim3(32, NBH), dim3(256), 0, stream>>>(Qf, Kf, Vt, wattn, Of);

  proj_gemm<2><<<gg, dim3(256), 0, stream>>>(Of, Wo16, bo, 1.0f, nullptr, out0);
}